// Round 11
// baseline (21.174 us; speedup 1.0000x reference)
//
#include <hip/hip_runtime.h>
#include <hip/hip_bf16.h>

#define NBATCH 1024
#define LSEQ   200
#define DD     16
#define LTT    10
#define LSCH   5
#define NCC    100

#define XT_S   232   // xt [16][232]: x^T [d][l], cols 200..207 zeroed
#define KT_S   24    // kt [208][24]: Kflat rows [j][p^swz], rows 200..207 zeroed

#define QSCALE 0.3606737602f   // 0.25 * log2(e)

typedef __bf16 bf16_4 __attribute__((ext_vector_type(4)));
typedef float  f32x4  __attribute__((ext_vector_type(4)));
typedef short  short4v __attribute__((ext_vector_type(4)));
typedef unsigned int uint2v __attribute__((ext_vector_type(2)));

__device__ __forceinline__ int kswz(int j) { return ((j >> 3) ^ (j >> 6)) & 1; }

__device__ __forceinline__ f32x4 mfma16(bf16_4 a, bf16_4 b, f32x4 c) {
#if __has_builtin(__builtin_amdgcn_mfma_f32_16x16x16bf16_1k)
    return __builtin_amdgcn_mfma_f32_16x16x16bf16_1k(
        __builtin_bit_cast(short4v, a), __builtin_bit_cast(short4v, b), c, 0, 0, 0);
#else
    uint2v au = __builtin_bit_cast(uint2v, a);
    uint2v bu = __builtin_bit_cast(uint2v, b);
    asm("v_mfma_f32_16x16x16_bf16 %0, %1, %2, %0" : "+v"(c) : "v"(au), "v"(bu));
    return c;
#endif
}

__global__ __launch_bounds__(256, 4) void hin_kernel(
    const int*   __restrict__ user_idx,
    const int*   __restrict__ user_sequence,
    const int*   __restrict__ user_teachers,
    const int*   __restrict__ user_school,
    const float* __restrict__ user_len_teacher,
    const float* __restrict__ user_len_school,
    const int*   __restrict__ course_set,
    const float* __restrict__ user_table,
    const float* __restrict__ course_table,
    const float* __restrict__ teacher_table,
    const float* __restrict__ school_table,
    const float* __restrict__ Qw, const float* __restrict__ Qb,
    const float* __restrict__ Kw, const float* __restrict__ Kb,
    const float* __restrict__ g1w, const float* __restrict__ g1b,
    const float* __restrict__ g2w, const float* __restrict__ g2b,
    float*       __restrict__ out)
{
    __shared__ __align__(16) __bf16 xt[DD * XT_S];
    __shared__ __align__(16) __bf16 kt[208 * KT_S];
    __shared__ float red[4][DD];
    __shared__ __align__(16) float tot12t[64];   // [row q][wave] tile-12 denom partials
    __shared__ float uf[DD];
    __shared__ float gst[800];       // g1w(512) | g1b(16) | g2w(256) | g2b(16)
    __shared__ float rows_pre[256];  // ue(16) | ut(160) | us(80)
    __shared__ float lens[2];

    const int b    = blockIdx.x;
    const int t    = threadIdx.x;
    const int w    = t >> 6;
    const int lane = t & 63;
    const int grp  = lane >> 4;
    const int li   = lane & 15;

    // ============ fused phase 0+1+2: NO internal barriers ======================
    if (t < 128)  // xt cols 200..207 zero
        xt[(t >> 3)*XT_S + 200 + (t & 7)] = (__bf16)0.f;
    else {        // kt rows 200..207 cols 0..15 zero
        const int i = t - 128;
        kt[(200 + (i >> 4))*KT_S + (i & 15)] = (__bf16)0.f;
    }
    for (int i = t; i < 800; i += 256) {
        float v;
        if      (i < 512) v = g1w[i];
        else if (i < 528) v = g1b[i - 512];
        else if (i < 784) v = g2w[i - 528];
        else              v = g2b[i - 784];
        gst[i] = v;
    }
    if (t < 16)       rows_pre[t] = user_table[user_idx[b]*DD + t];
    else if (t < 176) { const int i = t - 16;
        rows_pre[t] = teacher_table[user_teachers[b*LTT + (i >> 4)]*DD + (i & 15)]; }
    else if (t < 256) { const int i = t - 176;
        rows_pre[t] = school_table[user_school[b*LSCH + (i >> 4)]*DD + (i & 15)]; }
    if (t == 0) { lens[0] = user_len_teacher[b]; lens[1] = user_len_school[b]; }

    // ---- gather x -> xt (transposed bf16), consumed only after the barrier ----
    for (int e = t; e < 800; e += 256) {
        const int l = e >> 2, dq = e & 3;
        const int idx = user_sequence[b*LSEQ + l];
        const float4 v = *(const float4*)&course_table[idx*DD + dq*4];
        xt[(dq*4+0)*XT_S + l] = (__bf16)v.x;
        xt[(dq*4+1)*XT_S + l] = (__bf16)v.y;
        xt[(dq*4+2)*XT_S + l] = (__bf16)v.z;
        xt[(dq*4+3)*XT_S + l] = (__bf16)v.w;
    }

    const int wu = __builtin_amdgcn_readfirstlane(w);   // scalar wave id
    const int dr = li - grp*4;

    // ---- Q,K via MFMA, operands straight from global (no LDS reads) ----------
    bf16_4 qf0, qf1, qf2, qf12;
    {
        bf16_4 wq, wk;
        #pragma unroll
        for (int e = 0; e < 4; e++) {
            wq[e] = (__bf16)(Qw[(grp*4 + e)*DD + li] * QSCALE);
            wk[e] = (__bf16)(Kw[(grp*4 + e)*DD + li]);
        }
        const float4 qb4 = *(const float4*)&Qb[grp*4];
        float qbias[4] = {qb4.x*QSCALE, qb4.y*QSCALE, qb4.z*QSCALE, qb4.w*QSCALE};
        const float kbias = Kb[li];

        auto compute_qk = [&](int l0, bf16_4& qout, bool do_scatter) {
            const int lrow = l0 + li;
            const int idx = (lrow < LSEQ) ? user_sequence[b*LSEQ + lrow] : 0;
            const float4 xv = *(const float4*)&course_table[idx*DD + grp*4];
            bf16_4 xf;
            xf[0] = (__bf16)xv.x; xf[1] = (__bf16)xv.y;
            xf[2] = (__bf16)xv.z; xf[3] = (__bf16)xv.w;
            const f32x4 zc = {0.f, 0.f, 0.f, 0.f};
            f32x4 qv = mfma16(wq, xf, zc);   // lane -> QSCALE*Q[l0+li][grp*4+r]
            f32x4 kv = mfma16(xf, wk, zc);   // lane -> K[l0+grp*4+r][li]
            #pragma unroll
            for (int r = 0; r < 4; r++)
                qout[r] = (__bf16)fmaxf(qv[r] + qbias[r], 0.f);
            if (do_scatter) {
                #pragma unroll
                for (int r = 0; r < 4; r++) {
                    const int krow = l0 + grp*4 + r;
                    if (krow < LSEQ) {
                        const float val = fmaxf(kv[r] + kbias, 0.f);
                        const int f = krow*DD + li;
                        const int p = f / 200;
                        const int j = f - p*200;
                        kt[j*KT_S + (p ^ (kswz(j) << 3))] = (__bf16)val;
                    }
                }
            }
        };
        compute_qk(wu*16,       qf0, true);
        compute_qk((wu+4)*16,   qf1, true);
        compute_qk((wu+8)*16,   qf2, true);
        compute_qk(192,         qf12, wu == 0);
    }
    __syncthreads();   // xt + kt ready

    // ============ phase 3: 4 tiles interleaved; kf/xb from LDS (low VGPR) =====
    bf16_4 onesb;
    #pragma unroll
    for (int i = 0; i < 4; i++) onesb[i] = (__bf16)1.0f;

    const int mt0 = wu, mt1 = wu + 4, mt2 = wu + 8;
    const int jlo = (wu == 0) ? 0 : (3*wu + 1);
    const int jhi = 3*wu + 4;

    f32x4 ao0 = {0.f,0.f,0.f,0.f}, aD0 = {0.f,0.f,0.f,0.f};
    f32x4 ao1 = {0.f,0.f,0.f,0.f}, aD1 = {0.f,0.f,0.f,0.f};
    f32x4 ao2 = {0.f,0.f,0.f,0.f}, aD2 = {0.f,0.f,0.f,0.f};
    f32x4 ao3 = {0.f,0.f,0.f,0.f}, aD3 = {0.f,0.f,0.f,0.f};

    #pragma unroll
    for (int jt = 0; jt < 13; jt++) {
        const int jr = jt*16 + li;
        const bf16_4 kf = *(const bf16_4*)&kt[jr*KT_S + ((grp*4) ^ (kswz(jr) << 3))];
        const bf16_4 xb = *(const bf16_4*)&xt[li*XT_S + jt*16 + grp*4];
        const f32x4 zc = {0.f, 0.f, 0.f, 0.f};
        f32x4 s0 = mfma16(kf, qf0, zc);
        f32x4 s1 = mfma16(kf, qf1, zc);
        f32x4 s2 = mfma16(kf, qf2, zc);
        bf16_4 p0, p1, p2;
        #pragma unroll
        for (int r = 0; r < 4; r++) {
            float v0 = __builtin_amdgcn_exp2f(s0[r]);
            float v1 = __builtin_amdgcn_exp2f(s1[r]);
            float v2 = __builtin_amdgcn_exp2f(s2[r]);
            if (jt == 12 && grp >= 2) { v0 = 0.f; v1 = 0.f; v2 = 0.f; }
            if (jt == mt0 && dr == r) v0 = 1.0f;
            if (jt == mt1 && dr == r) v1 = 1.0f;
            if (jt == mt2 && dr == r) v2 = 1.0f;
            p0[r] = (__bf16)v0; p1[r] = (__bf16)v1; p2[r] = (__bf16)v2;
        }
        aD0 = mfma16(p0, onesb, aD0);  ao0 = mfma16(p0, xb, ao0);
        aD1 = mfma16(p1, onesb, aD1);  ao1 = mfma16(p1, xb, ao1);
        aD2 = mfma16(p2, onesb, aD2);  ao2 = mfma16(p2, xb, ao2);
        if (jt >= jlo && jt < jhi) {             // tile-12 slice (scalar guard)
            f32x4 s3 = mfma16(kf, qf12, zc);
            bf16_4 p3;
            #pragma unroll
            for (int r = 0; r < 4; r++) {
                float v3 = __builtin_amdgcn_exp2f(s3[r]);
                if (jt == 12 && grp >= 2) v3 = 0.f;
                if (jt == 12 && dr == r)  v3 = 1.0f;
                p3[r] = (__bf16)v3;
            }
            aD3 = mfma16(p3, onesb, aD3);  ao3 = mfma16(p3, xb, ao3);
        }
    }

    float wsum = 0.f;
    #pragma unroll
    for (int r = 0; r < 4; r++) {
        wsum += ao0[r] * __builtin_amdgcn_rcpf(aD0[r]);
        wsum += ao1[r] * __builtin_amdgcn_rcpf(aD1[r]);
        wsum += ao2[r] * __builtin_amdgcn_rcpf(aD2[r]);
    }
    if (li == 0) {                            // aD3[r] uniform across li
        #pragma unroll
        for (int r = 0; r < 4; r++)
            tot12t[(grp*4 + r)*4 + w] = aD3[r];
    }
    __syncthreads();

    #pragma unroll
    for (int r = 0; r < 4; r++) {
        const int q = grp*4 + r;                 // row 192+q
        const float4 p4 = *(const float4*)&tot12t[q*4];
        const float dsum = (p4.x + p4.y) + (p4.z + p4.w);
        if (192 + q < LSEQ)
            wsum += ao3[r] * __builtin_amdgcn_rcpf(dsum);
    }

    wsum += __shfl_xor(wsum, 16);
    wsum += __shfl_xor(wsum, 32);
    if (lane < DD) red[w][lane] = wsum;
    __syncthreads();

    // ============ epilogue prefetch: issue course-row loads under the MLP ======
    float4 ce0, ce1, ce2, ce3;
    if (t < NCC) {
        const int ci = course_set[b*NCC + t];
        const float* ce = &course_table[ci*DD];
        ce0 = *(const float4*)&ce[0];
        ce1 = *(const float4*)&ce[4];
        ce2 = *(const float4*)&ce[8];
        ce3 = *(const float4*)&ce[12];
    }

    // ============ phase 4: MLP in wave 0 via shuffles ==========================
    if (w == 0) {
        const float ue  = rows_pre[li];
        const float seq = (red[0][li] + red[1][li] + red[2][li] + red[3][li]) * (1.0f / LSEQ);
        float uts = 0.f;
        #pragma unroll
        for (int i = 0; i < LTT; i++)  uts += rows_pre[16 + i*16 + li];
        float uss = 0.f;
        #pragma unroll
        for (int i = 0; i < LSCH; i++) uss += rows_pre[176 + i*16 + li];
        const float agg = (seq + uts / lens[0] + uss / lens[1]) * (1.0f / 3.0f);
        float a1 = gst[512 + li];
        #pragma unroll
        for (int k = 0; k < 16; k++) a1 = fmaf(__shfl(ue,  k), gst[k*DD + li], a1);
        #pragma unroll
        for (int k = 0; k < 16; k++) a1 = fmaf(__shfl(agg, k), gst[(16 + k)*DD + li], a1);
        const float hidv = fmaxf(a1, 0.f);
        float a2 = gst[784 + li];
        #pragma unroll
        for (int k = 0; k < 16; k++) a2 = fmaf(__shfl(hidv, k), gst[528 + k*DD + li], a2);
        if (lane < DD) uf[lane] = a2;
    }
    __syncthreads();

    // ============ epilogue: dot with prefetched rows ===========================
    if (t < NCC) {
        const float4 u0 = *(const float4*)&uf[0];
        const float4 u1 = *(const float4*)&uf[4];
        const float4 u2 = *(const float4*)&uf[8];
        const float4 u3 = *(const float4*)&uf[12];
        float s = ce0.x*u0.x + ce0.y*u0.y + ce0.z*u0.z + ce0.w*u0.w;
        s      += ce1.x*u1.x + ce1.y*u1.y + ce1.z*u1.z + ce1.w*u1.w;
        s      += ce2.x*u2.x + ce2.y*u2.y + ce2.z*u2.z + ce2.w*u2.w;
        s      += ce3.x*u3.x + ce3.y*u3.y + ce3.z*u3.z + ce3.w*u3.w;
        out[b*NCC + t] = s;
    }
}

extern "C" void kernel_launch(void* const* d_in, const int* in_sizes, int n_in,
                              void* d_out, int out_size, void* d_ws, size_t ws_size,
                              hipStream_t stream) {
    const int*   user_idx         = (const int*)  d_in[0];
    const int*   user_sequence    = (const int*)  d_in[1];
    const int*   user_teachers    = (const int*)  d_in[2];
    const int*   user_school      = (const int*)  d_in[3];
    const float* user_len_teacher = (const float*)d_in[5];
    const float* user_len_school  = (const float*)d_in[6];
    const int*   course_set       = (const int*)  d_in[7];
    const float* user_table       = (const float*)d_in[13];
    const float* course_table     = (const float*)d_in[14];
    const float* teacher_table    = (const float*)d_in[15];
    const float* school_table     = (const float*)d_in[16];
    const float* Qw  = (const float*)d_in[17];
    const float* Qb  = (const float*)d_in[18];
    const float* Kw  = (const float*)d_in[19];
    const float* Kb  = (const float*)d_in[20];
    const float* g1w = (const float*)d_in[21];
    const float* g1b = (const float*)d_in[22];
    const float* g2w = (const float*)d_in[23];
    const float* g2b = (const float*)d_in[24];

    float* outp = (float*)d_out;

    hipLaunchKernelGGL(hin_kernel, dim3(NBATCH), dim3(256), 0, stream,
                       user_idx, user_sequence, user_teachers, user_school,
                       user_len_teacher, user_len_school, course_set,
                       user_table, course_table, teacher_table, school_table,
                       Qw, Qb, Kw, Kb, g1w, g1b, g2w, g2b, outp);
}

// Round 12
// 20.234 us; speedup vs baseline: 1.0464x; 1.0464x over previous
//
#include <hip/hip_runtime.h>
#include <hip/hip_bf16.h>

#define NBATCH 1024
#define LSEQ   200
#define DD     16
#define LTT    10
#define LSCH   5
#define NCC    100

#define XT_S   232   // xt [16][232]: x^T [d][l], cols 200..207 zeroed
#define KT_S   24    // kt [208][24]: Kflat rows [j][p^swz], rows 200..207 zeroed

#define QSCALE 0.3606737602f   // 0.25 * log2(e)

typedef __bf16 bf16_4 __attribute__((ext_vector_type(4)));
typedef float  f32x4  __attribute__((ext_vector_type(4)));
typedef short  short4v __attribute__((ext_vector_type(4)));
typedef unsigned int uint2v __attribute__((ext_vector_type(2)));

__device__ __forceinline__ int kswz(int j) { return ((j >> 3) ^ (j >> 6)) & 1; }

__device__ __forceinline__ f32x4 mfma16(bf16_4 a, bf16_4 b, f32x4 c) {
#if __has_builtin(__builtin_amdgcn_mfma_f32_16x16x16bf16_1k)
    return __builtin_amdgcn_mfma_f32_16x16x16bf16_1k(
        __builtin_bit_cast(short4v, a), __builtin_bit_cast(short4v, b), c, 0, 0, 0);
#else
    uint2v au = __builtin_bit_cast(uint2v, a);
    uint2v bu = __builtin_bit_cast(uint2v, b);
    asm("v_mfma_f32_16x16x16_bf16 %0, %1, %2, %0" : "+v"(c) : "v"(au), "v"(bu));
    return c;
#endif
}

__global__ __launch_bounds__(256, 4) void hin_kernel(
    const int*   __restrict__ user_idx,
    const int*   __restrict__ user_sequence,
    const int*   __restrict__ user_teachers,
    const int*   __restrict__ user_school,
    const float* __restrict__ user_len_teacher,
    const float* __restrict__ user_len_school,
    const int*   __restrict__ course_set,
    const float* __restrict__ user_table,
    const float* __restrict__ course_table,
    const float* __restrict__ teacher_table,
    const float* __restrict__ school_table,
    const float* __restrict__ Qw, const float* __restrict__ Qb,
    const float* __restrict__ Kw, const float* __restrict__ Kb,
    const float* __restrict__ g1w, const float* __restrict__ g1b,
    const float* __restrict__ g2w, const float* __restrict__ g2b,
    float*       __restrict__ out)
{
    __shared__ __align__(16) __bf16 xt[DD * XT_S];
    __shared__ __align__(16) __bf16 kt[208 * KT_S];
    __shared__ float red[4][DD];
    __shared__ __align__(16) float tot12t[64];   // [row q][wave] tile-12 denom partials
    __shared__ float uf[DD];
    __shared__ float gst[800];       // g1w(512) | g1b(16) | g2w(256) | g2b(16)
    __shared__ float rows_pre[256];  // ue(16) | ut(160) | us(80)
    __shared__ float lens[2];

    const int b    = blockIdx.x;
    const int t    = threadIdx.x;
    const int w    = t >> 6;
    const int lane = t & 63;
    const int grp  = lane >> 4;
    const int li   = lane & 15;

    // ============ fused prologue: single-pass gather + Q/K, no internal barrier =
    if (t < 128)  // xt cols 200..207 zero
        xt[(t >> 3)*XT_S + 200 + (t & 7)] = (__bf16)0.f;
    else {        // kt rows 200..207 cols 0..15 zero
        const int i = t - 128;
        kt[(200 + (i >> 4))*KT_S + (i & 15)] = (__bf16)0.f;
    }
    for (int i = t; i < 800; i += 256) {
        float v;
        if      (i < 512) v = g1w[i];
        else if (i < 528) v = g1b[i - 512];
        else if (i < 784) v = g2w[i - 528];
        else              v = g2b[i - 784];
        gst[i] = v;
    }
    if (t < 16)       rows_pre[t] = user_table[user_idx[b]*DD + t];
    else if (t < 176) { const int i = t - 16;
        rows_pre[t] = teacher_table[user_teachers[b*LTT + (i >> 4)]*DD + (i & 15)]; }
    else if (t < 256) { const int i = t - 176;
        rows_pre[t] = school_table[user_school[b*LSCH + (i >> 4)]*DD + (i & 15)]; }
    if (t == 0) { lens[0] = user_len_teacher[b]; lens[1] = user_len_school[b]; }

    const int wu = __builtin_amdgcn_readfirstlane(w);   // scalar wave id
    const int dr = li - grp*4;

    // ---- Q,K via MFMA straight from global; x scattered to xt as a side effect -
    bf16_4 qf0, qf1, qf2, qf12;
    {
        bf16_4 wq, wk;
        #pragma unroll
        for (int e = 0; e < 4; e++) {
            wq[e] = (__bf16)(Qw[(grp*4 + e)*DD + li] * QSCALE);
            wk[e] = (__bf16)(Kw[(grp*4 + e)*DD + li]);
        }
        const float4 qb4 = *(const float4*)&Qb[grp*4];
        float qbias[4] = {qb4.x*QSCALE, qb4.y*QSCALE, qb4.z*QSCALE, qb4.w*QSCALE};
        const float kbias = Kb[li];

        auto compute_qk = [&](int l0, bf16_4& qout, bool do_scatter) {
            const int lrow = l0 + li;
            const int idx = (lrow < LSEQ) ? user_sequence[b*LSEQ + lrow] : 0;
            const float4 xv = *(const float4*)&course_table[idx*DD + grp*4];
            bf16_4 xf;
            xf[0] = (__bf16)xv.x; xf[1] = (__bf16)xv.y;
            xf[2] = (__bf16)xv.z; xf[3] = (__bf16)xv.w;
            if (do_scatter && lrow < LSEQ) {
                // transpose-scatter this fragment into xt (covers all of x once)
                #pragma unroll
                for (int e = 0; e < 4; e++)
                    xt[(grp*4 + e)*XT_S + lrow] = xf[e];
            }
            const f32x4 zc = {0.f, 0.f, 0.f, 0.f};
            f32x4 qv = mfma16(wq, xf, zc);   // lane -> QSCALE*Q[l0+li][grp*4+r]
            f32x4 kv = mfma16(xf, wk, zc);   // lane -> K[l0+grp*4+r][li]
            #pragma unroll
            for (int r = 0; r < 4; r++)
                qout[r] = (__bf16)fmaxf(qv[r] + qbias[r], 0.f);
            if (do_scatter) {
                #pragma unroll
                for (int r = 0; r < 4; r++) {
                    const int krow = l0 + grp*4 + r;
                    if (krow < LSEQ) {
                        const float val = fmaxf(kv[r] + kbias, 0.f);
                        const int f = krow*DD + li;
                        const int p = f / 200;
                        const int j = f - p*200;
                        kt[j*KT_S + (p ^ (kswz(j) << 3))] = (__bf16)val;
                    }
                }
            }
        };
        compute_qk(wu*16,       qf0, true);
        compute_qk((wu+4)*16,   qf1, true);
        compute_qk((wu+8)*16,   qf2, true);
        compute_qk(192,         qf12, wu == 0);   // wave 0 also scatters tile-12 x/K
    }
    __syncthreads();   // xt + kt ready

    // ============ phase 3: 4 tiles interleaved; kf/xb from LDS =================
    bf16_4 onesb;
    #pragma unroll
    for (int i = 0; i < 4; i++) onesb[i] = (__bf16)1.0f;

    const int mt0 = wu, mt1 = wu + 4, mt2 = wu + 8;
    const int jlo = (wu == 0) ? 0 : (3*wu + 1);
    const int jhi = 3*wu + 4;

    f32x4 ao0 = {0.f,0.f,0.f,0.f}, aD0 = {0.f,0.f,0.f,0.f};
    f32x4 ao1 = {0.f,0.f,0.f,0.f}, aD1 = {0.f,0.f,0.f,0.f};
    f32x4 ao2 = {0.f,0.f,0.f,0.f}, aD2 = {0.f,0.f,0.f,0.f};
    f32x4 ao3 = {0.f,0.f,0.f,0.f}, aD3 = {0.f,0.f,0.f,0.f};

    #pragma unroll
    for (int jt = 0; jt < 13; jt++) {
        const int jr = jt*16 + li;
        const bf16_4 kf = *(const bf16_4*)&kt[jr*KT_S + ((grp*4) ^ (kswz(jr) << 3))];
        const bf16_4 xb = *(const bf16_4*)&xt[li*XT_S + jt*16 + grp*4];
        const f32x4 zc = {0.f, 0.f, 0.f, 0.f};
        f32x4 s0 = mfma16(kf, qf0, zc);
        f32x4 s1 = mfma16(kf, qf1, zc);
        f32x4 s2 = mfma16(kf, qf2, zc);
        bf16_4 p0, p1, p2;
        #pragma unroll
        for (int r = 0; r < 4; r++) {
            float v0 = __builtin_amdgcn_exp2f(s0[r]);
            float v1 = __builtin_amdgcn_exp2f(s1[r]);
            float v2 = __builtin_amdgcn_exp2f(s2[r]);
            if (jt == 12 && grp >= 2) { v0 = 0.f; v1 = 0.f; v2 = 0.f; }
            if (jt == mt0 && dr == r) v0 = 1.0f;
            if (jt == mt1 && dr == r) v1 = 1.0f;
            if (jt == mt2 && dr == r) v2 = 1.0f;
            p0[r] = (__bf16)v0; p1[r] = (__bf16)v1; p2[r] = (__bf16)v2;
        }
        aD0 = mfma16(p0, onesb, aD0);  ao0 = mfma16(p0, xb, ao0);
        aD1 = mfma16(p1, onesb, aD1);  ao1 = mfma16(p1, xb, ao1);
        aD2 = mfma16(p2, onesb, aD2);  ao2 = mfma16(p2, xb, ao2);
        if (jt >= jlo && jt < jhi) {             // tile-12 slice (scalar guard)
            f32x4 s3 = mfma16(kf, qf12, zc);
            bf16_4 p3;
            #pragma unroll
            for (int r = 0; r < 4; r++) {
                float v3 = __builtin_amdgcn_exp2f(s3[r]);
                if (jt == 12 && grp >= 2) v3 = 0.f;
                if (jt == 12 && dr == r)  v3 = 1.0f;
                p3[r] = (__bf16)v3;
            }
            aD3 = mfma16(p3, onesb, aD3);  ao3 = mfma16(p3, xb, ao3);
        }
    }

    float wsum = 0.f;
    #pragma unroll
    for (int r = 0; r < 4; r++) {
        wsum += ao0[r] * __builtin_amdgcn_rcpf(aD0[r]);
        wsum += ao1[r] * __builtin_amdgcn_rcpf(aD1[r]);
        wsum += ao2[r] * __builtin_amdgcn_rcpf(aD2[r]);
    }
    if (li == 0) {                            // aD3[r] uniform across li
        #pragma unroll
        for (int r = 0; r < 4; r++)
            tot12t[(grp*4 + r)*4 + w] = aD3[r];
    }
    __syncthreads();

    #pragma unroll
    for (int r = 0; r < 4; r++) {
        const int q = grp*4 + r;                 // row 192+q
        const float4 p4 = *(const float4*)&tot12t[q*4];
        const float dsum = (p4.x + p4.y) + (p4.z + p4.w);
        if (192 + q < LSEQ)
            wsum += ao3[r] * __builtin_amdgcn_rcpf(dsum);
    }

    wsum += __shfl_xor(wsum, 16);
    wsum += __shfl_xor(wsum, 32);
    if (lane < DD) red[w][lane] = wsum;
    __syncthreads();

    // ============ epilogue prefetch: issue course-row loads under the MLP ======
    float4 ce0, ce1, ce2, ce3;
    if (t < NCC) {
        const int ci = course_set[b*NCC + t];
        const float* ce = &course_table[ci*DD];
        ce0 = *(const float4*)&ce[0];
        ce1 = *(const float4*)&ce[4];
        ce2 = *(const float4*)&ce[8];
        ce3 = *(const float4*)&ce[12];
    }

    // ============ phase 4: MLP in wave 0 via shuffles ==========================
    if (w == 0) {
        const float ue  = rows_pre[li];
        const float seq = (red[0][li] + red[1][li] + red[2][li] + red[3][li]) * (1.0f / LSEQ);
        float uts = 0.f;
        #pragma unroll
        for (int i = 0; i < LTT; i++)  uts += rows_pre[16 + i*16 + li];
        float uss = 0.f;
        #pragma unroll
        for (int i = 0; i < LSCH; i++) uss += rows_pre[176 + i*16 + li];
        const float agg = (seq + uts / lens[0] + uss / lens[1]) * (1.0f / 3.0f);
        float a1 = gst[512 + li];
        #pragma unroll
        for (int k = 0; k < 16; k++) a1 = fmaf(__shfl(ue,  k), gst[k*DD + li], a1);
        #pragma unroll
        for (int k = 0; k < 16; k++) a1 = fmaf(__shfl(agg, k), gst[(16 + k)*DD + li], a1);
        const float hidv = fmaxf(a1, 0.f);
        float a2 = gst[784 + li];
        #pragma unroll
        for (int k = 0; k < 16; k++) a2 = fmaf(__shfl(hidv, k), gst[528 + k*DD + li], a2);
        if (lane < DD) uf[lane] = a2;
    }
    __syncthreads();

    // ============ epilogue: dot with prefetched rows ===========================
    if (t < NCC) {
        const float4 u0 = *(const float4*)&uf[0];
        const float4 u1 = *(const float4*)&uf[4];
        const float4 u2 = *(const float4*)&uf[8];
        const float4 u3 = *(const float4*)&uf[12];
        float s = ce0.x*u0.x + ce0.y*u0.y + ce0.z*u0.z + ce0.w*u0.w;
        s      += ce1.x*u1.x + ce1.y*u1.y + ce1.z*u1.z + ce1.w*u1.w;
        s      += ce2.x*u2.x + ce2.y*u2.y + ce2.z*u2.z + ce2.w*u2.w;
        s      += ce3.x*u3.x + ce3.y*u3.y + ce3.z*u3.z + ce3.w*u3.w;
        out[b*NCC + t] = s;
    }
}

extern "C" void kernel_launch(void* const* d_in, const int* in_sizes, int n_in,
                              void* d_out, int out_size, void* d_ws, size_t ws_size,
                              hipStream_t stream) {
    const int*   user_idx         = (const int*)  d_in[0];
    const int*   user_sequence    = (const int*)  d_in[1];
    const int*   user_teachers    = (const int*)  d_in[2];
    const int*   user_school      = (const int*)  d_in[3];
    const float* user_len_teacher = (const float*)d_in[5];
    const float* user_len_school  = (const float*)d_in[6];
    const int*   course_set       = (const int*)  d_in[7];
    const float* user_table       = (const float*)d_in[13];
    const float* course_table     = (const float*)d_in[14];
    const float* teacher_table    = (const float*)d_in[15];
    const float* school_table     = (const float*)d_in[16];
    const float* Qw  = (const float*)d_in[17];
    const float* Qb  = (const float*)d_in[18];
    const float* Kw  = (const float*)d_in[19];
    const float* Kb  = (const float*)d_in[20];
    const float* g1w = (const float*)d_in[21];
    const float* g1b = (const float*)d_in[22];
    const float* g2w = (const float*)d_in[23];
    const float* g2b = (const float*)d_in[24];

    float* outp = (float*)d_out;

    hipLaunchKernelGGL(hin_kernel, dim3(NBATCH), dim3(256), 0, stream,
                       user_idx, user_sequence, user_teachers, user_school,
                       user_len_teacher, user_len_school, course_set,
                       user_table, course_table, teacher_table, school_table,
                       Qw, Qb, Kw, Kb, g1w, g1b, g2w, g2b, outp);
}